// Round 7
// baseline (12916.949 us; speedup 1.0000x reference)
//
#include <hip/hip_runtime.h>
#include <hip/hip_bf16.h>
#include <math.h>

typedef __attribute__((ext_vector_type(4))) float vf4;
typedef __attribute__((ext_vector_type(8))) short vbf8;
typedef __attribute__((ext_vector_type(8))) unsigned short vus8;

#define NWG   32
#define NTHR  1024
#define LEN   1024
#define H3    3072
#define CND   80
#define EMBD  128

// ---- ws byte offsets ----
#define TAB1_B  0ull
#define TAB2_B  (TAB1_B + 786432ull*4)
#define TAB3_B  (TAB2_B + 786432ull*4)
#define BF_B    (TAB3_B + 786432ull*4)            // bfrag: 128oct*2which*35frag*512 bf16
#define MELA_B  (BF_B   + 4587520ull*2)           // melA : 1024t*2m*3frag*512 bf16
#define AF_B    (MELA_B + 3145728ull*2)           // Afrag: 1025t*64frag*512 bf16
#define CNT_B   (AF_B   + 33587200ull*2)          // 32 epoch slots, 64B apart
#define FOFS    8388608ull                        // flogits offset in d_out

// ============================ prep kernels (unchanged) ============================

__global__ __launch_bounds__(256) void make_tables(const float* __restrict__ IW,
                                                   const float* __restrict__ Ib,
                                                   const float* __restrict__ cemb,
                                                   const float* __restrict__ femb,
                                                   float* __restrict__ tab1,
                                                   float* __restrict__ tab2,
                                                   float* __restrict__ tab3) {
    int blk = blockIdx.x;
    int table = blk / 3072;
    int rem = blk % 3072;
    int row = rem / 12;
    int cc = rem % 12;
    int col = cc * 256 + threadIdx.x;
    int ofs = CND + table * EMBD;
    const float* emb = (table == 1) ? femb : cemb;
    float acc = 0.f;
    for (int k = 0; k < EMBD; ++k)
        acc += emb[row * EMBD + k] * IW[(size_t)(ofs + k) * H3 + col];
    if (table == 0) acc += Ib[col];
    if (table == 2 && ((col & 1023) < 768)) acc = 0.f;
    float* dst = (table == 0) ? tab1 : (table == 1 ? tab2 : tab3);
    dst[(size_t)row * H3 + col] = acc;
}

// B frag layout: [octet 0..127][which 0..1][kk 0..34][lane 0..63][elem 0..7]
__global__ __launch_bounds__(256) void build_bfrag(const float* __restrict__ Rw,
                                                   const float* __restrict__ IW,
                                                   const float* __restrict__ Rb,
                                                   unsigned short* __restrict__ Bf) {
    long idx = (long)blockIdx.x * 256 + threadIdx.x;
    int elem = idx & 7;
    int lane = (idx >> 3) & 63;
    int kk   = (int)((idx >> 9) % 35);
    int n    = (int)((idx / (512 * 35)) & 1);
    int oc   = (int)(idx / (512 * 35 * 2));
    int c    = lane & 15;
    int k    = kk * 32 + ((lane >> 4) & 3) * 8 + elem;
    int jj   = oc * 8 + (c & 7);
    float v = 0.f;
    if (n == 0) {
        int col = (c >> 3) * 1024 + jj;
        if (k < 1024)       v = Rw[(size_t)k * H3 + col];
        else if (k < 1104)  v = IW[(size_t)(k - 1024) * H3 + col];
        else if (k == 1104) v = Rb[col];
    } else {
        if ((c >> 3) == 0) {
            if (k < 1024)       v = Rw[(size_t)k * H3 + 2048 + jj];
            else if (k == 1104) v = Rb[2048 + jj];
        } else {
            if (k >= 1024 && k < 1104) v = IW[(size_t)(k - 1024) * H3 + 2048 + jj];
        }
    }
    __hip_bfloat16 hb = __float2bfloat16(v);
    Bf[idx] = *(unsigned short*)&hb;
}

__global__ __launch_bounds__(256) void build_melA(const float* __restrict__ mel,
                                                  unsigned short* __restrict__ MelA) {
    long idx = (long)blockIdx.x * 256 + threadIdx.x;
    int elem = idx & 7;
    int lane = (idx >> 3) & 63;
    int kkm  = (int)((idx >> 9) % 3);
    int m    = (int)((idx / 1536) & 1);
    int t    = (int)(idx / 3072);
    int b    = m * 16 + (lane & 15);
    int km   = kkm * 32 + ((lane >> 4) & 3) * 8 + elem;
    float v = (km < CND) ? mel[((size_t)b * LEN + t) * CND + km] : (km == CND ? 1.f : 0.f);
    __hip_bfloat16 hb = __float2bfloat16(v);
    MelA[idx] = *(unsigned short*)&hb;
}

// ============================ persistent scan ============================
// 32 WGs x 1024 thr (16 waves, 1 WG/CU). Coherence (NO invalidates ever):
//  - h (Af): written write-through via relaxed agent atomic u32 stores; pulled
//    ONCE per WG per step via relaxed agent atomic u64 loads into LDS (dedupe),
//    then all waves ds_read their MFMA fragments from LDS.
//  - Tables / Bf / MelA / xin: immutable -> normal cached loads, L1/L2-hot
//    across all 1024 steps (never invalidated).
//  - Barrier: per-WG epoch slot (64B apart), RELEASE store after syncthreads
//    (vmcnt0 drains h stores); wave-0 32-lane relaxed poll + ballot.
__global__ __launch_bounds__(1024, 1) void scan_persist(const unsigned short* __restrict__ Bf,
                                                        const unsigned short* __restrict__ MelA,
                                                        unsigned short* __restrict__ Af,
                                                        const float* __restrict__ tab1,
                                                        const float* __restrict__ tab2,
                                                        const float* __restrict__ tab3,
                                                        const int* __restrict__ xin,
                                                        unsigned int* __restrict__ cnt) {
    __shared__ unsigned short hbuf[64 * 512];   // 64 KB: Af[t] staged
    __shared__ float ex[32][136];               // 17.4 KB: pre-act exchange

    int tid = threadIdx.x;
    int wg  = blockIdx.x;
    int lane = tid & 63;
    int wv = tid >> 6;            // 0..15
    int m  = wv >> 3;             // A half (batch 0-15 / 16-31)
    int ow = wv & 7;
    int oct_l = ow >> 1;          // 0..3: local 8-j octet
    int which = ow & 1;           // 0: [u|r], 1: [e1|e2]
    int oct = wg * 4 + oct_l;     // global octet

    // B fragments (cached loads, L2-hot forever)
    const unsigned short* Bp = Bf + (((size_t)oct * 2 + which) * 35) * 512 + lane * 8;
    vbf8 Breg[35];
#pragma unroll
    for (int kk = 0; kk < 35; ++kk)
        Breg[kk] = *(const vbf8*)(Bp + kk * 512);

    // gate role: one (b, j) per thread
    int gb = tid >> 5, gjl = tid & 31;
    int gj = wg * 32 + gjl;
    float hreg = 0.f;
    size_t wbase = (size_t)(((gb >> 4) * 32 + (gj >> 5)) * 512 +
                            ((gb & 15) + 16 * ((gjl >> 3) & 3)) * 8 + (gjl & 7));

    // phase-A carried state
    float tsu = 0.f, tsr = 0.f, tse = 0.f;
    vf4 amel = {0.f, 0.f, 0.f, 0.f};

#define PHASE_A(tt) do {                                                          \
        int ci = xin[(gb * LEN + (tt)) * 2];                                      \
        int fi = xin[(gb * LEN + (tt)) * 2 + 1];                                  \
        int cn = xin[(gb * LEN + (((tt) + 1) & (LEN - 1))) * 2];                  \
        const float* p1 = tab1 + (size_t)ci * H3 + gj;                            \
        const float* p2 = tab2 + (size_t)fi * H3 + gj;                            \
        const float* p3 = tab3 + (size_t)cn * H3 + gj;                            \
        float a1u = p1[0],    a2u = p2[0],    a3u = p3[0];                        \
        float a1r = p1[1024], a2r = p2[1024], a3r = p3[1024];                     \
        float a1e = p1[2048], a2e = p2[2048], a3e = p3[2048];                     \
        tsu = a1u + a2u + a3u;                                                    \
        tsr = a1r + a2r + a3r;                                                    \
        tse = a1e + a2e + a3e;                                                    \
        const unsigned short* Am = MelA + (size_t)(tt) * 3072 +                   \
                                   (size_t)(m * 3) * 512 + lane * 8;              \
        vf4 am = {0.f, 0.f, 0.f, 0.f};                                            \
        _Pragma("unroll")                                                         \
        for (int kq = 0; kq < 3; ++kq) {                                          \
            vbf8 a = *(const vbf8*)(Am + kq * 512);                               \
            am = __builtin_amdgcn_mfma_f32_16x16x32_bf16(a, Breg[32 + kq], am,    \
                                                         0, 0, 0);                \
        }                                                                         \
        amel = am;                                                                \
    } while (0)

    // cooperative pull of Af[tt] (64 KB) into hbuf: wave wv takes frags wv*4..+3
#define PULL(tt) do {                                                             \
        unsigned long long q[8];                                                  \
        _Pragma("unroll")                                                         \
        for (int i = 0; i < 4; ++i) {                                             \
            const unsigned long long* sp = (const unsigned long long*)            \
                (Af + (size_t)(tt) * 32768 + (size_t)(wv * 4 + i) * 512) + lane * 2; \
            q[2 * i]     = __hip_atomic_load(sp,     __ATOMIC_RELAXED,            \
                                             __HIP_MEMORY_SCOPE_AGENT);           \
            q[2 * i + 1] = __hip_atomic_load(sp + 1, __ATOMIC_RELAXED,            \
                                             __HIP_MEMORY_SCOPE_AGENT);           \
        }                                                                         \
        _Pragma("unroll")                                                         \
        for (int i = 0; i < 4; ++i) {                                             \
            union { unsigned long long qq[2]; vus8 v; } u;                        \
            u.qq[0] = q[2 * i]; u.qq[1] = q[2 * i + 1];                           \
            *(vus8*)(hbuf + (size_t)(wv * 4 + i) * 512 + lane * 8) = u.v;         \
        }                                                                         \
    } while (0)

    PHASE_A(0);
    PULL(0);
    __syncthreads();

#pragma unroll 1
    for (int t = 0; t < LEN; ++t) {
        // ---- D(16x16) = h(16x1024) x B + carried mel/bias part (A from LDS) ----
        const unsigned short* Ah = hbuf + (size_t)(m * 32) * 512 + lane * 8;
        vf4 acc0 = amel, acc1 = {0.f, 0.f, 0.f, 0.f};
#pragma unroll
        for (int kk = 0; kk < 32; kk += 2) {
            vbf8 a0 = *(const vbf8*)(Ah + kk * 512);
            acc0 = __builtin_amdgcn_mfma_f32_16x16x32_bf16(a0, Breg[kk], acc0, 0, 0, 0);
            vbf8 a1 = *(const vbf8*)(Ah + (kk + 1) * 512);
            acc1 = __builtin_amdgcn_mfma_f32_16x16x32_bf16(a1, Breg[kk + 1], acc1, 0, 0, 0);
        }
        vf4 acc = acc0 + acc1;

        // ---- exchange pre-activations (C: col=lane&15, row=(lane>>4)*4+r) ----
#pragma unroll
        for (int r = 0; r < 4; ++r)
            ex[m * 16 + ((lane >> 4) * 4 + r)][oct_l * 32 + which * 16 + (lane & 15)] = acc[r];
        __syncthreads();

        // ---- gates + state update (one (b,j) per thread) ----
        int oc4 = gjl >> 3, jo = gjl & 7;
        float gu  = ex[gb][oc4 * 32 + jo]      + tsu;
        float gr  = ex[gb][oc4 * 32 + 8 + jo]  + tsr;
        float e1  = ex[gb][oc4 * 32 + 16 + jo];
        float ge2 = ex[gb][oc4 * 32 + 24 + jo] + tse;
        float u  = 1.f / (1.f + expf(-gu));
        float r_ = 1.f / (1.f + expf(-gr));
        float e  = tanhf(r_ * e1 + ge2);
        hreg = u * hreg + (1.f - u) * e;

        // ---- coherent packed store of h (pair via shfl) ----
        __hip_bfloat16 hb = __float2bfloat16(hreg);
        int myv = (int)(*(unsigned short*)&hb);
        int nbv = __shfl_xor(myv, 1);
        if ((tid & 1) == 0) {
            unsigned int pk = ((unsigned)myv & 0xffffu) | ((unsigned)nbv << 16);
            __hip_atomic_store((unsigned int*)(Af + (size_t)(t + 1) * 32768 + wbase), pk,
                               __ATOMIC_RELAXED, __HIP_MEMORY_SCOPE_AGENT);
        }

        // ---- arrive: all waves' h-stores drained (vmcnt0) before slot store ----
        __syncthreads();
        if (tid == 0)
            __hip_atomic_store(&cnt[wg * 16], (unsigned)(t + 1),
                               __ATOMIC_RELEASE, __HIP_MEMORY_SCOPE_AGENT);

        if (t + 1 < LEN) {
            // ---- phase A for t+1 (independent of h[t+1]; cached loads) ----
            PHASE_A(t + 1);

            // ---- wait: wave 0, lanes 0..31 poll the 32 slots; ballot ----
            if (wv == 0) {
                unsigned tgt = (unsigned)(t + 1);
                for (;;) {
                    unsigned v = tgt;
                    if (lane < 32)
                        v = __hip_atomic_load(&cnt[lane * 16], __ATOMIC_RELAXED,
                                              __HIP_MEMORY_SCOPE_AGENT);
                    if (__all((int)(v >= tgt))) break;
                    __builtin_amdgcn_s_sleep(1);
                }
            }
            __syncthreads();
            asm volatile("" ::: "memory");

            // ---- pull h[t+1] once per WG into LDS (always-fresh atomics) ----
            PULL(t + 1);
            __syncthreads();
        }
    }
#undef PHASE_A
#undef PULL
}

// ============================ output MLPs (unchanged) ============================
#define LOADF4(arr, ptr) { float4 _v = *(const float4*)(ptr); arr[0]=_v.x; arr[1]=_v.y; arr[2]=_v.z; arr[3]=_v.w; }

__device__ __forceinline__ void load_y8(const unsigned short* __restrict__ Af,
                                        int tslot, int b, int kk, float* o) {
    size_t off = (size_t)tslot * 32768 +
                 (size_t)(((b >> 4) * 32 + (kk >> 5)) * 512) +
                 (size_t)(((b & 15) + 16 * ((kk >> 3) & 3)) * 8);
    vus8 v = *(const vus8*)(Af + off);
#pragma unroll
    for (int e = 0; e < 8; ++e) o[e] = __uint_as_float(((unsigned)v[e]) << 16);
}

__global__ __launch_bounds__(256) void out_mlp(const unsigned short* __restrict__ Af,
                                               const float* __restrict__ O1w, const float* __restrict__ O1b,
                                               const float* __restrict__ O2w, const float* __restrict__ O2b,
                                               const float* __restrict__ O3w, const float* __restrict__ O3b,
                                               const float* __restrict__ O4w, const float* __restrict__ O4b,
                                               float* __restrict__ out) {
    __shared__ float z[16][768];
    int tid = threadIdx.x;
    int ig = tid >> 6;
    int lane = tid & 63;
    int R0 = blockIdx.x * 16;

    int rb[4], rt[4];
#pragma unroll
    for (int i = 0; i < 4; ++i) {
        int R = R0 + ig * 4 + i;
        rb[i] = R >> 10;
        rt[i] = (R & 1023) + 1;
    }

    for (int pass = 0; pass < 3; ++pass) {
        int c = pass * 256 + lane * 4;
        float acc[4][4];
#pragma unroll
        for (int i = 0; i < 4; ++i)
#pragma unroll
            for (int jj = 0; jj < 4; ++jj) acc[i][jj] = O1b[c + jj];
        for (int kk = 0; kk < 768; kk += 8) {
            float w[8][4];
#pragma unroll
            for (int dk = 0; dk < 8; ++dk) LOADF4(w[dk], &O1w[(size_t)(kk + dk) * 768 + c]);
            float ya[4][8];
#pragma unroll
            for (int i = 0; i < 4; ++i) load_y8(Af, rt[i], rb[i], kk, ya[i]);
#pragma unroll
            for (int i = 0; i < 4; ++i)
#pragma unroll
                for (int dk = 0; dk < 8; ++dk)
#pragma unroll
                    for (int jj = 0; jj < 4; ++jj)
                        acc[i][jj] += ya[i][dk] * w[dk][jj];
        }
#pragma unroll
        for (int i = 0; i < 4; ++i)
#pragma unroll
            for (int jj = 0; jj < 4; ++jj)
                z[ig * 4 + i][c + jj] = fmaxf(acc[i][jj], 0.f);
    }
    __syncthreads();

    {
        int c = lane * 4;
        float acc[4][4];
#pragma unroll
        for (int i = 0; i < 4; ++i)
#pragma unroll
            for (int jj = 0; jj < 4; ++jj) acc[i][jj] = O2b[c + jj];
        for (int kk = 0; kk < 768; kk += 4) {
            float w[4][4];
#pragma unroll
            for (int dk = 0; dk < 4; ++dk) LOADF4(w[dk], &O2w[(size_t)(kk + dk) * 256 + c]);
            float za[4][4];
#pragma unroll
            for (int i = 0; i < 4; ++i) LOADF4(za[i], &z[ig * 4 + i][kk]);
#pragma unroll
            for (int i = 0; i < 4; ++i)
#pragma unroll
                for (int dk = 0; dk < 4; ++dk)
#pragma unroll
                    for (int jj = 0; jj < 4; ++jj)
                        acc[i][jj] += za[i][dk] * w[dk][jj];
        }
#pragma unroll
        for (int i = 0; i < 4; ++i) {
            int R = R0 + ig * 4 + i;
#pragma unroll
            for (int jj = 0; jj < 4; ++jj)
                out[(size_t)R * 256 + c + jj] = acc[i][jj];
        }
    }
    __syncthreads();

    {
        int c = lane * 4;
        float acc[4][4];
#pragma unroll
        for (int i = 0; i < 4; ++i)
#pragma unroll
            for (int jj = 0; jj < 4; ++jj) acc[i][jj] = O3b[c + jj];
        for (int kk = 0; kk < 256; kk += 8) {
            float w[8][4];
#pragma unroll
            for (int dk = 0; dk < 8; ++dk) LOADF4(w[dk], &O3w[(size_t)(kk + dk) * 256 + c]);
            float ya[4][8];
#pragma unroll
            for (int i = 0; i < 4; ++i) load_y8(Af, rt[i], rb[i], 768 + kk, ya[i]);
#pragma unroll
            for (int i = 0; i < 4; ++i)
#pragma unroll
                for (int dk = 0; dk < 8; ++dk)
#pragma unroll
                    for (int jj = 0; jj < 4; ++jj)
                        acc[i][jj] += ya[i][dk] * w[dk][jj];
        }
        __syncthreads();
#pragma unroll
        for (int i = 0; i < 4; ++i)
#pragma unroll
            for (int jj = 0; jj < 4; ++jj)
                z[ig * 4 + i][c + jj] = fmaxf(acc[i][jj], 0.f);
    }
    __syncthreads();

    {
        int c = lane * 4;
        float acc[4][4];
#pragma unroll
        for (int i = 0; i < 4; ++i)
#pragma unroll
            for (int jj = 0; jj < 4; ++jj) acc[i][jj] = O4b[c + jj];
        for (int kk = 0; kk < 256; kk += 4) {
            float w[4][4];
#pragma unroll
            for (int dk = 0; dk < 4; ++dk) LOADF4(w[dk], &O4w[(size_t)(kk + dk) * 256 + c]);
            float za[4][4];
#pragma unroll
            for (int i = 0; i < 4; ++i) LOADF4(za[i], &z[ig * 4 + i][kk]);
#pragma unroll
            for (int i = 0; i < 4; ++i)
#pragma unroll
                for (int dk = 0; dk < 4; ++dk)
#pragma unroll
                    for (int jj = 0; jj < 4; ++jj)
                        acc[i][jj] += za[i][dk] * w[dk][jj];
        }
#pragma unroll
        for (int i = 0; i < 4; ++i) {
            int R = R0 + ig * 4 + i;
#pragma unroll
            for (int jj = 0; jj < 4; ++jj)
                out[FOFS + (size_t)R * 256 + c + jj] = acc[i][jj];
        }
    }
}

// ============================ launch ============================
extern "C" void kernel_launch(void* const* d_in, const int* in_sizes, int n_in,
                              void* d_out, int out_size, void* d_ws, size_t ws_size,
                              hipStream_t stream) {
    const int*   x    = (const int*)d_in[0];
    const float* mel  = (const float*)d_in[1];
    const float* Rw   = (const float*)d_in[2];
    const float* Rb   = (const float*)d_in[3];
    const float* IW   = (const float*)d_in[4];
    const float* Ib   = (const float*)d_in[5];
    const float* O1w  = (const float*)d_in[6];
    const float* O1b  = (const float*)d_in[7];
    const float* O2w  = (const float*)d_in[8];
    const float* O2b  = (const float*)d_in[9];
    const float* O3w  = (const float*)d_in[10];
    const float* O3b  = (const float*)d_in[11];
    const float* O4w  = (const float*)d_in[12];
    const float* O4b  = (const float*)d_in[13];
    const float* cemb = (const float*)d_in[14];
    const float* femb = (const float*)d_in[15];
    char* wsb = (char*)d_ws;
    float* out = (float*)d_out;

    float* tab1 = (float*)(wsb + TAB1_B);
    float* tab2 = (float*)(wsb + TAB2_B);
    float* tab3 = (float*)(wsb + TAB3_B);
    unsigned short* Bf   = (unsigned short*)(wsb + BF_B);
    unsigned short* MelA = (unsigned short*)(wsb + MELA_B);
    unsigned short* Af   = (unsigned short*)(wsb + AF_B);
    unsigned int*   cnt  = (unsigned int*)(wsb + CNT_B);

    make_tables<<<9216, 256, 0, stream>>>(IW, Ib, cemb, femb, tab1, tab2, tab3);
    build_bfrag<<<17920, 256, 0, stream>>>(Rw, IW, Rb, Bf);
    build_melA<<<12288, 256, 0, stream>>>(mel, MelA);
    hipMemsetAsync((void*)Af, 0, 65536, stream);   // h0 = 0
    hipMemsetAsync((void*)cnt, 0, 4096, stream);   // epoch slots

    scan_persist<<<NWG, NTHR, 0, stream>>>(Bf, MelA, Af, tab1, tab2, tab3, x, cnt);

    out_mlp<<<2048, 256, 0, stream>>>(Af, O1w, O1b, O2w, O2b, O3w, O3b, O4w, O4b, out);
}

// Round 9
// 6646.109 us; speedup vs baseline: 1.9435x; 1.9435x over previous
//
#include <hip/hip_runtime.h>
#include <hip/hip_bf16.h>
#include <math.h>

typedef __attribute__((ext_vector_type(4))) float vf4;
typedef __attribute__((ext_vector_type(8))) short vbf8;
typedef __attribute__((ext_vector_type(8))) unsigned short vus8;

#define NWG   128
#define NTHR  256
#define LEN   1024
#define H3    3072
#define CND   80
#define EMBD  128

// ---- ws byte offsets ----
#define TAB1_B  0ull
#define TAB2_B  (TAB1_B + 786432ull*4)
#define TAB3_B  (TAB2_B + 786432ull*4)
#define BF_B    (TAB3_B + 786432ull*4)            // bfrag: 128oct*2which*35frag*512 bf16
#define MELA_B  (BF_B   + 4587520ull*2)           // melA : 1024t*2m*3frag*512 bf16
#define AF_B    (MELA_B + 3145728ull*2)           // Afrag: 1025t*64frag*512 bf16
#define CNT_B   (AF_B   + 33587200ull*2)          // 8 counters, 256B apart
#define FOFS    8388608ull                        // flogits offset in d_out

// ============================ prep kernels (unchanged) ============================

__global__ __launch_bounds__(256) void make_tables(const float* __restrict__ IW,
                                                   const float* __restrict__ Ib,
                                                   const float* __restrict__ cemb,
                                                   const float* __restrict__ femb,
                                                   float* __restrict__ tab1,
                                                   float* __restrict__ tab2,
                                                   float* __restrict__ tab3) {
    int blk = blockIdx.x;
    int table = blk / 3072;
    int rem = blk % 3072;
    int row = rem / 12;
    int cc = rem % 12;
    int col = cc * 256 + threadIdx.x;
    int ofs = CND + table * EMBD;
    const float* emb = (table == 1) ? femb : cemb;
    float acc = 0.f;
    for (int k = 0; k < EMBD; ++k)
        acc += emb[row * EMBD + k] * IW[(size_t)(ofs + k) * H3 + col];
    if (table == 0) acc += Ib[col];
    if (table == 2 && ((col & 1023) < 768)) acc = 0.f;
    float* dst = (table == 0) ? tab1 : (table == 1 ? tab2 : tab3);
    dst[(size_t)row * H3 + col] = acc;
}

// B frag layout: [octet 0..127][which 0..1][kk 0..34][lane 0..63][elem 0..7]
__global__ __launch_bounds__(256) void build_bfrag(const float* __restrict__ Rw,
                                                   const float* __restrict__ IW,
                                                   const float* __restrict__ Rb,
                                                   unsigned short* __restrict__ Bf) {
    long idx = (long)blockIdx.x * 256 + threadIdx.x;
    int elem = idx & 7;
    int lane = (idx >> 3) & 63;
    int kk   = (int)((idx >> 9) % 35);
    int n    = (int)((idx / (512 * 35)) & 1);
    int oc   = (int)(idx / (512 * 35 * 2));
    int c    = lane & 15;
    int k    = kk * 32 + ((lane >> 4) & 3) * 8 + elem;
    int jj   = oc * 8 + (c & 7);
    float v = 0.f;
    if (n == 0) {
        int col = (c >> 3) * 1024 + jj;
        if (k < 1024)       v = Rw[(size_t)k * H3 + col];
        else if (k < 1104)  v = IW[(size_t)(k - 1024) * H3 + col];
        else if (k == 1104) v = Rb[col];
    } else {
        if ((c >> 3) == 0) {
            if (k < 1024)       v = Rw[(size_t)k * H3 + 2048 + jj];
            else if (k == 1104) v = Rb[2048 + jj];
        } else {
            if (k >= 1024 && k < 1104) v = IW[(size_t)(k - 1024) * H3 + 2048 + jj];
        }
    }
    __hip_bfloat16 hb = __float2bfloat16(v);
    Bf[idx] = *(unsigned short*)&hb;
}

__global__ __launch_bounds__(256) void build_melA(const float* __restrict__ mel,
                                                  unsigned short* __restrict__ MelA) {
    long idx = (long)blockIdx.x * 256 + threadIdx.x;
    int elem = idx & 7;
    int lane = (idx >> 3) & 63;
    int kkm  = (int)((idx >> 9) % 3);
    int m    = (int)((idx / 1536) & 1);
    int t    = (int)(idx / 3072);
    int b    = m * 16 + (lane & 15);
    int km   = kkm * 32 + ((lane >> 4) & 3) * 8 + elem;
    float v = (km < CND) ? mel[((size_t)b * LEN + t) * CND + km] : (km == CND ? 1.f : 0.f);
    __hip_bfloat16 hb = __float2bfloat16(v);
    MelA[idx] = *(unsigned short*)&hb;
}

// ============================ persistent scan ============================
// 128 WGs x 256 thr (4 waves, 2m x 2n). Both MFMA operands live in LDS:
//  - B (70KB): staged ONCE at kernel start (sync'd before ANY use, incl.
//    PHASE_A(0) -- r8's bug); LDS is immune to the per-step acquire-fence
//    invalidate -> zero per-step B traffic.
//  - A = h[t] (64KB): pulled once per WG per step (reg-staged, coalesced),
//    then all 4 waves ds_read fragments (vs 4x duplicated cache reads).
//  - Barrier: r4's measured-best scheme (8 spread RMW counters, RELEASE add;
//    relaxed ballot poll; ONE agent-acquire fence). Phase-A (tables + mel
//    MFMA from LDS-B) overlaps the wait.
__global__ __launch_bounds__(256, 1) void scan_persist(const unsigned short* __restrict__ Bf,
                                                       const unsigned short* __restrict__ MelA,
                                                       unsigned short* __restrict__ Af,
                                                       const float* __restrict__ tab1,
                                                       const float* __restrict__ tab2,
                                                       const float* __restrict__ tab3,
                                                       const int* __restrict__ xin,
                                                       unsigned int* __restrict__ cnt) {
    __shared__ __align__(16) unsigned short Bs[2 * 35 * 512];   // 71,680 B
    __shared__ __align__(16) unsigned short hstage[64 * 512];   // 65,536 B
    __shared__ float ex[32][36];                                //  4,608 B

    int tid = threadIdx.x;
    int wg  = blockIdx.x;
    int lane = tid & 63;
    int wv = tid >> 6;            // 0..3
    int m  = wv >> 1;             // A half (batch 0-15 / 16-31)
    int n  = wv & 1;              // 0: [u|r] cols, 1: [e1|e2] cols

    // ---- stage this WG's B fragments into LDS (one-time) ----
    {
        const unsigned int* src = (const unsigned int*)(Bf + (size_t)wg * (2 * 35 * 512));
        unsigned int* dst = (unsigned int*)Bs;
#pragma unroll
        for (int i = 0; i < 70; ++i) dst[tid + i * 256] = src[tid + i * 256];
    }
    __syncthreads();   // Bs complete before ANY read (PHASE_A(0) reads it!) -- r8 bugfix

    // gate role: one (b, j) per thread
    int gb = tid >> 3, gjl = tid & 7;
    int gj = wg * 8 + gjl;
    float hreg = 0.f;
    size_t wbase = (size_t)(((gb >> 4) * 32 + (gj >> 5)) * 512 +
                            ((gb & 15) + 16 * ((gj >> 3) & 3)) * 8 + (gj & 7));

    // phase-A carried state
    float tsu = 0.f, tsr = 0.f, tse = 0.f;
    vf4 amel = {0.f, 0.f, 0.f, 0.f};

    const unsigned short* Bn = Bs + (n * 35) * 512 + lane * 8;

#define PHASE_A(tt) do {                                                          \
        int ci = xin[(gb * LEN + (tt)) * 2];                                      \
        int fi = xin[(gb * LEN + (tt)) * 2 + 1];                                  \
        int cn = xin[(gb * LEN + (((tt) + 1) & (LEN - 1))) * 2];                  \
        const float* p1 = tab1 + (size_t)ci * H3 + gj;                            \
        const float* p2 = tab2 + (size_t)fi * H3 + gj;                            \
        const float* p3 = tab3 + (size_t)cn * H3 + gj;                            \
        float a1u = p1[0],    a2u = p2[0],    a3u = p3[0];                        \
        float a1r = p1[1024], a2r = p2[1024], a3r = p3[1024];                     \
        float a1e = p1[2048], a2e = p2[2048], a3e = p3[2048];                     \
        tsu = a1u + a2u + a3u;                                                    \
        tsr = a1r + a2r + a3r;                                                    \
        tse = a1e + a2e + a3e;                                                    \
        const unsigned short* Am = MelA + (size_t)(tt) * 3072 +                   \
                                   (size_t)(m * 3) * 512 + lane * 8;              \
        vf4 am = {0.f, 0.f, 0.f, 0.f};                                            \
        _Pragma("unroll")                                                         \
        for (int kq = 0; kq < 3; ++kq) {                                          \
            vbf8 a = *(const vbf8*)(Am + kq * 512);                               \
            vbf8 b = *(const vbf8*)(Bn + (32 + kq) * 512);                        \
            am = __builtin_amdgcn_mfma_f32_16x16x32_bf16(a, b, am, 0, 0, 0);      \
        }                                                                         \
        amel = am;                                                                \
    } while (0)

    // cooperative pull of Af[tt] (64 KB) into hstage: reg-staged, coalesced
#define PULL(tt) do {                                                             \
        const vus8* src = (const vus8*)(Af + (size_t)(tt) * 32768) + tid;         \
        vus8* dst = (vus8*)hstage + tid;                                          \
        vus8 tmp[8];                                                              \
        _Pragma("unroll")                                                         \
        for (int r = 0; r < 8; ++r) tmp[r] = src[r * 256];                        \
        _Pragma("unroll")                                                         \
        for (int r = 0; r < 8; ++r) dst[r * 256] = tmp[r];                        \
        _Pragma("unroll")                                                         \
        for (int r = 8; r < 16; ++r) tmp[r - 8] = src[r * 256];                   \
        _Pragma("unroll")                                                         \
        for (int r = 8; r < 16; ++r) dst[r * 256] = tmp[r - 8];                   \
    } while (0)

    PHASE_A(0);
    PULL(0);
    __syncthreads();

#pragma unroll 1
    for (int t = 0; t < LEN; ++t) {
        // ---- D(16x16) = h(16x1024) x B + carried mel/bias part (A,B from LDS) ----
        const unsigned short* Ah = hstage + (size_t)(m * 32) * 512 + lane * 8;
        vf4 acc0 = amel, acc1 = {0.f, 0.f, 0.f, 0.f};
#pragma unroll
        for (int kk = 0; kk < 32; kk += 2) {
            vbf8 a0 = *(const vbf8*)(Ah + kk * 512);
            vbf8 b0 = *(const vbf8*)(Bn + kk * 512);
            acc0 = __builtin_amdgcn_mfma_f32_16x16x32_bf16(a0, b0, acc0, 0, 0, 0);
            vbf8 a1 = *(const vbf8*)(Ah + (kk + 1) * 512);
            vbf8 b1 = *(const vbf8*)(Bn + (kk + 1) * 512);
            acc1 = __builtin_amdgcn_mfma_f32_16x16x32_bf16(a1, b1, acc1, 0, 0, 0);
        }
        vf4 acc = acc0 + acc1;

        // ---- exchange pre-activations (C: col=lane&15, row=(lane>>4)*4+r) ----
#pragma unroll
        for (int r = 0; r < 4; ++r)
            ex[m * 16 + ((lane >> 4) * 4 + r)][n * 16 + (lane & 15)] = acc[r];
        __syncthreads();

        // ---- gates + state update ----
        float gu  = ex[gb][gjl]      + tsu;
        float gr  = ex[gb][8 + gjl]  + tsr;
        float e1  = ex[gb][16 + gjl];
        float ge2 = ex[gb][24 + gjl] + tse;
        float u  = 1.f / (1.f + expf(-gu));
        float r_ = 1.f / (1.f + expf(-gr));
        float e  = tanhf(r_ * e1 + ge2);
        hreg = u * hreg + (1.f - u) * e;

        // ---- coherent packed store of h (pair via shfl) ----
        __hip_bfloat16 hb = __float2bfloat16(hreg);
        int myv = (int)(*(unsigned short*)&hb);
        int nbv = __shfl_xor(myv, 1);
        if ((tid & 1) == 0) {
            unsigned int pk = ((unsigned)myv & 0xffffu) | ((unsigned)nbv << 16);
            __hip_atomic_store((unsigned int*)(Af + (size_t)(t + 1) * 32768 + wbase), pk,
                               __ATOMIC_RELAXED, __HIP_MEMORY_SCOPE_AGENT);
        }

        // ---- arrive: all h-stores drained (syncthreads => vmcnt0) ----
        __syncthreads();
        if (tid == 0)
            __hip_atomic_fetch_add(&cnt[(wg & 7) * 64], 1u,
                                   __ATOMIC_RELEASE, __HIP_MEMORY_SCOPE_AGENT);

        if (t + 1 < LEN) {
            // ---- phase A for t+1 (independent of h[t+1]) ----
            PHASE_A(t + 1);

            // ---- wait: wave 0, lanes 0..7 poll the 8 counters; ballot ----
            if (tid < 64) {
                unsigned tgt = (unsigned)(t + 1) * 16;   // 16 WGs per counter
                for (;;) {
                    unsigned v = tgt;
                    if (lane < 8)
                        v = __hip_atomic_load(&cnt[lane * 64], __ATOMIC_RELAXED,
                                              __HIP_MEMORY_SCOPE_AGENT);
                    if (__all((int)(v >= tgt))) break;
                    __builtin_amdgcn_s_sleep(1);
                }
                __builtin_amdgcn_fence(__ATOMIC_ACQUIRE, "agent");  // ONE L2 inv/step
            }
            __syncthreads();
            asm volatile("" ::: "memory");

            // ---- pull h[t+1] into LDS (post-fence cached loads = fresh) ----
            PULL(t + 1);
            __syncthreads();
        }
    }
#undef PHASE_A
#undef PULL
}

// ============================ output MLPs (unchanged) ============================
#define LOADF4(arr, ptr) { float4 _v = *(const float4*)(ptr); arr[0]=_v.x; arr[1]=_v.y; arr[2]=_v.z; arr[3]=_v.w; }

__device__ __forceinline__ void load_y8(const unsigned short* __restrict__ Af,
                                        int tslot, int b, int kk, float* o) {
    size_t off = (size_t)tslot * 32768 +
                 (size_t)(((b >> 4) * 32 + (kk >> 5)) * 512) +
                 (size_t)(((b & 15) + 16 * ((kk >> 3) & 3)) * 8);
    vus8 v = *(const vus8*)(Af + off);
#pragma unroll
    for (int e = 0; e < 8; ++e) o[e] = __uint_as_float(((unsigned)v[e]) << 16);
}

__global__ __launch_bounds__(256) void out_mlp(const unsigned short* __restrict__ Af,
                                               const float* __restrict__ O1w, const float* __restrict__ O1b,
                                               const float* __restrict__ O2w, const float* __restrict__ O2b,
                                               const float* __restrict__ O3w, const float* __restrict__ O3b,
                                               const float* __restrict__ O4w, const float* __restrict__ O4b,
                                               float* __restrict__ out) {
    __shared__ float z[16][768];
    int tid = threadIdx.x;
    int ig = tid >> 6;
    int lane = tid & 63;
    int R0 = blockIdx.x * 16;

    int rb[4], rt[4];
#pragma unroll
    for (int i = 0; i < 4; ++i) {
        int R = R0 + ig * 4 + i;
        rb[i] = R >> 10;
        rt[i] = (R & 1023) + 1;
    }

    for (int pass = 0; pass < 3; ++pass) {
        int c = pass * 256 + lane * 4;
        float acc[4][4];
#pragma unroll
        for (int i = 0; i < 4; ++i)
#pragma unroll
            for (int jj = 0; jj < 4; ++jj) acc[i][jj] = O1b[c + jj];
        for (int kk = 0; kk < 768; kk += 8) {
            float w[8][4];
#pragma unroll
            for (int dk = 0; dk < 8; ++dk) LOADF4(w[dk], &O1w[(size_t)(kk + dk) * 768 + c]);
            float ya[4][8];
#pragma unroll
            for (int i = 0; i < 4; ++i) load_y8(Af, rt[i], rb[i], kk, ya[i]);
#pragma unroll
            for (int i = 0; i < 4; ++i)
#pragma unroll
                for (int dk = 0; dk < 8; ++dk)
#pragma unroll
                    for (int jj = 0; jj < 4; ++jj)
                        acc[i][jj] += ya[i][dk] * w[dk][jj];
        }
#pragma unroll
        for (int i = 0; i < 4; ++i)
#pragma unroll
            for (int jj = 0; jj < 4; ++jj)
                z[ig * 4 + i][c + jj] = fmaxf(acc[i][jj], 0.f);
    }
    __syncthreads();

    {
        int c = lane * 4;
        float acc[4][4];
#pragma unroll
        for (int i = 0; i < 4; ++i)
#pragma unroll
            for (int jj = 0; jj < 4; ++jj) acc[i][jj] = O2b[c + jj];
        for (int kk = 0; kk < 768; kk += 4) {
            float w[4][4];
#pragma unroll
            for (int dk = 0; dk < 4; ++dk) LOADF4(w[dk], &O2w[(size_t)(kk + dk) * 256 + c]);
            float za[4][4];
#pragma unroll
            for (int i = 0; i < 4; ++i) LOADF4(za[i], &z[ig * 4 + i][kk]);
#pragma unroll
            for (int i = 0; i < 4; ++i)
#pragma unroll
                for (int dk = 0; dk < 4; ++dk)
#pragma unroll
                    for (int jj = 0; jj < 4; ++jj)
                        acc[i][jj] += za[i][dk] * w[dk][jj];
        }
#pragma unroll
        for (int i = 0; i < 4; ++i) {
            int R = R0 + ig * 4 + i;
#pragma unroll
            for (int jj = 0; jj < 4; ++jj)
                out[(size_t)R * 256 + c + jj] = acc[i][jj];
        }
    }
    __syncthreads();

    {
        int c = lane * 4;
        float acc[4][4];
#pragma unroll
        for (int i = 0; i < 4; ++i)
#pragma unroll
            for (int jj = 0; jj < 4; ++jj) acc[i][jj] = O3b[c + jj];
        for (int kk = 0; kk < 256; kk += 8) {
            float w[8][4];
#pragma unroll
            for (int dk = 0; dk < 8; ++dk) LOADF4(w[dk], &O3w[(size_t)(kk + dk) * 256 + c]);
            float ya[4][8];
#pragma unroll
            for (int i = 0; i < 4; ++i) load_y8(Af, rt[i], rb[i], 768 + kk, ya[i]);
#pragma unroll
            for (int i = 0; i < 4; ++i)
#pragma unroll
                for (int dk = 0; dk < 8; ++dk)
#pragma unroll
                    for (int jj = 0; jj < 4; ++jj)
                        acc[i][jj] += ya[i][dk] * w[dk][jj];
        }
        __syncthreads();
#pragma unroll
        for (int i = 0; i < 4; ++i)
#pragma unroll
            for (int jj = 0; jj < 4; ++jj)
                z[ig * 4 + i][c + jj] = fmaxf(acc[i][jj], 0.f);
    }
    __syncthreads();

    {
        int c = lane * 4;
        float acc[4][4];
#pragma unroll
        for (int i = 0; i < 4; ++i)
#pragma unroll
            for (int jj = 0; jj < 4; ++jj) acc[i][jj] = O4b[c + jj];
        for (int kk = 0; kk < 256; kk += 4) {
            float w[4][4];
#pragma unroll
            for (int dk = 0; dk < 4; ++dk) LOADF4(w[dk], &O4w[(size_t)(kk + dk) * 256 + c]);
            float za[4][4];
#pragma unroll
            for (int i = 0; i < 4; ++i) LOADF4(za[i], &z[ig * 4 + i][kk]);
#pragma unroll
            for (int i = 0; i < 4; ++i)
#pragma unroll
                for (int dk = 0; dk < 4; ++dk)
#pragma unroll
                    for (int jj = 0; jj < 4; ++jj)
                        acc[i][jj] += za[i][dk] * w[dk][jj];
        }
#pragma unroll
        for (int i = 0; i < 4; ++i) {
            int R = R0 + ig * 4 + i;
#pragma unroll
            for (int jj = 0; jj < 4; ++jj)
                out[FOFS + (size_t)R * 256 + c + jj] = acc[i][jj];
        }
    }
}

// ============================ launch ============================
extern "C" void kernel_launch(void* const* d_in, const int* in_sizes, int n_in,
                              void* d_out, int out_size, void* d_ws, size_t ws_size,
                              hipStream_t stream) {
    const int*   x    = (const int*)d_in[0];
    const float* mel  = (const float*)d_in[1];
    const float* Rw   = (const float*)d_in[2];
    const float* Rb   = (const float*)d_in[3];
    const float* IW   = (const float*)d_in[4];
    const float* Ib   = (const float*)d_in[5];
    const float* O1w  = (const float*)d_in[6];
    const float* O1b  = (const float*)d_in[7];
    const float* O2w  = (const float*)d_in[8];
    const float* O2b  = (const float*)d_in[9];
    const float* O3w  = (const float*)d_in[10];
    const float* O3b  = (const float*)d_in[11];
    const float* O4w  = (const float*)d_in[12];
    const float* O4b  = (const float*)d_in[13];
    const float* cemb = (const float*)d_in[14];
    const float* femb = (const float*)d_in[15];
    char* wsb = (char*)d_ws;
    float* out = (float*)d_out;

    float* tab1 = (float*)(wsb + TAB1_B);
    float* tab2 = (float*)(wsb + TAB2_B);
    float* tab3 = (float*)(wsb + TAB3_B);
    unsigned short* Bf   = (unsigned short*)(wsb + BF_B);
    unsigned short* MelA = (unsigned short*)(wsb + MELA_B);
    unsigned short* Af   = (unsigned short*)(wsb + AF_B);
    unsigned int*   cnt  = (unsigned int*)(wsb + CNT_B);

    make_tables<<<9216, 256, 0, stream>>>(IW, Ib, cemb, femb, tab1, tab2, tab3);
    build_bfrag<<<17920, 256, 0, stream>>>(Rw, IW, Rb, Bf);
    build_melA<<<12288, 256, 0, stream>>>(mel, MelA);
    hipMemsetAsync((void*)Af, 0, 65536, stream);   // h0 = 0
    hipMemsetAsync((void*)cnt, 0, 4096, stream);   // counters

    scan_persist<<<NWG, NTHR, 0, stream>>>(Bf, MelA, Af, tab1, tab2, tab3, x, cnt);

    out_mlp<<<2048, 256, 0, stream>>>(Af, O1w, O1b, O2w, O2b, O3w, O3b, O4w, O4b, out);
}